// Round 4
// baseline (406.679 us; speedup 1.0000x reference)
//
#include <hip/hip_runtime.h>
#include <math.h>

// CrossModalAttentionFusion: B=262144, D=32, 3 modality tokens, 4 heads.
// Established by rounds 0-3: all float tensors are float32, output is read
// back as float32, threshold = 2% * max|ref|. modality_masks (bool in the
// reference) has an ambiguous device encoding (int32 vs 1-byte) -> detect at
// runtime: scan mask words; any word not in {0,1} => byte-packed.
// One thread per sample; weights via wave-uniform indices (s_load path);
// head loop rolled to bound code size; out-proj folded per head.

#define NEGV (-1e9f)
#define LN_EPS 1e-5f

typedef unsigned int u32;

// detect: masks byte-packed (flag=1) or int32 (flag=0).
// Scans first nwords u32s -- must be valid under BOTH encodings.
__global__ void cmaf_detect(const u32* __restrict__ mw_words, u32* __restrict__ flag,
                            int nwords)
{
    int i = blockIdx.x * 256 + threadIdx.x;
    bool bad = false;
    #pragma unroll
    for (int k = 0; k < 4; ++k) {
        int idx = i * 4 + k;
        if (idx < nwords) { u32 w = mw_words[idx]; bad |= (w > 1u); }
    }
    unsigned long long any = __ballot(bad);
    if ((threadIdx.x & 63) == 0 && any) atomicOr(flag, 1u);
}

__global__ __launch_bounds__(256, 2) void cmaf_kernel(
    const float* __restrict__ metric,
    const float* __restrict__ logx,
    const float* __restrict__ trace,
    const void* __restrict__ masks_raw,   // [B,3] int32 or byte
    const u32*  __restrict__ flagp,
    const float* __restrict__ Win,     // [96,32]
    const float* __restrict__ bin,     // [96]
    const float* __restrict__ Wout,    // [32,32]
    const float* __restrict__ bout,    // [32]
    const float* __restrict__ mw,      // [3]
    const float* __restrict__ gam,     // [32]
    const float* __restrict__ bet,     // [32]
    float* __restrict__ out,           // [B,32] f32
    int B)
{
    int b = blockIdx.x * 256 + threadIdx.x;
    if (b >= B) return;

    bool m0, m1, m2;
    if (*flagp) {  // byte-packed bools
        const unsigned char* mb = (const unsigned char*)masks_raw;
        m0 = mb[3*b+0] != 0; m1 = mb[3*b+1] != 0; m2 = mb[3*b+2] != 0;
    } else {       // int32
        const int* mi = (const int*)masks_raw;
        m0 = mi[3*b+0] != 0; m1 = mi[3*b+1] != 0; m2 = mi[3*b+2] != 0;
    }
    const int count = (int)m0 + (int)m1 + (int)m2;

    // ---- load features f[3][32] (float4 vectorized) ----
    float f[3][32];
    {
        const float4* p0 = reinterpret_cast<const float4*>(metric + (size_t)b*32);
        const float4* p1 = reinterpret_cast<const float4*>(logx   + (size_t)b*32);
        const float4* p2 = reinterpret_cast<const float4*>(trace  + (size_t)b*32);
        #pragma unroll
        for (int i = 0; i < 8; ++i) {
            float4 a = p0[i];
            f[0][4*i+0]=a.x; f[0][4*i+1]=a.y; f[0][4*i+2]=a.z; f[0][4*i+3]=a.w;
            float4 c = p1[i];
            f[1][4*i+0]=c.x; f[1][4*i+1]=c.y; f[1][4*i+2]=c.z; f[1][4*i+3]=c.w;
            float4 d = p2[i];
            f[2][4*i+0]=d.x; f[2][4*i+1]=d.y; f[2][4*i+2]=d.z; f[2][4*i+3]=d.w;
        }
    }

    float4* po = reinterpret_cast<float4*>(out + (size_t)b*32);

    // ---- count 0 or 1: output = sum(features * mask) ----
    if (count <= 1) {
        const float fm0 = m0 ? 1.f : 0.f;
        const float fm1 = m1 ? 1.f : 0.f;
        const float fm2 = m2 ? 1.f : 0.f;
        #pragma unroll
        for (int i = 0; i < 8; ++i) {
            float4 r;
            r.x = fm0*f[0][4*i+0] + fm1*f[1][4*i+0] + fm2*f[2][4*i+0];
            r.y = fm0*f[0][4*i+1] + fm1*f[1][4*i+1] + fm2*f[2][4*i+1];
            r.z = fm0*f[0][4*i+2] + fm1*f[1][4*i+2] + fm2*f[2][4*i+2];
            r.w = fm0*f[0][4*i+3] + fm1*f[1][4*i+3] + fm2*f[2][4*i+3];
            po[i] = r;
        }
        return;
    }

    // ---- modal-weight softmax over available modalities ----
    float w0, w1, w2;
    {
        float l0 = m0 ? mw[0] : NEGV;
        float l1 = m1 ? mw[1] : NEGV;
        float l2 = m2 ? mw[2] : NEGV;
        float mx = fmaxf(l0, fmaxf(l1, l2));
        float e0 = __expf(l0 - mx), e1 = __expf(l1 - mx), e2 = __expf(l2 - mx);
        float inv = 1.f / (e0 + e1 + e2);
        w0 = e0*inv; w1 = e1*inv; w2 = e2*inv;
    }

    // ---- attention: per-head qkv + 3x3 softmax + ctx, out-proj folded in ----
    float acc[3][32];
    #pragma unroll
    for (int s = 0; s < 3; ++s)
        #pragma unroll
        for (int o = 0; o < 32; ++o) acc[s][o] = 0.f;

    const float scale = 0.35355339059327373f;  // 1/sqrt(8)

    #pragma unroll 1
    for (int h = 0; h < 4; ++h) {
        float kk[3][8], vv[3][8];
        #pragma unroll
        for (int s = 0; s < 3; ++s) {
            #pragma unroll
            for (int d = 0; d < 8; ++d) {
                const int r = h*8 + d;                 // uniform -> s_load
                float ak = bin[32 + r];
                float av = bin[64 + r];
                const float* wkr = Win + (size_t)(32 + r)*32;
                const float* wvr = Win + (size_t)(64 + r)*32;
                #pragma unroll
                for (int j = 0; j < 32; ++j) {
                    float x = f[s][j];
                    ak = fmaf(x, wkr[j], ak);
                    av = fmaf(x, wvr[j], av);
                }
                kk[s][d] = ak; vv[s][d] = av;
            }
        }
        float ctxh[3][8];
        #pragma unroll
        for (int sq = 0; sq < 3; ++sq) {
            float qd[8];
            #pragma unroll
            for (int d = 0; d < 8; ++d) {
                const int r = h*8 + d;
                float aq = bin[r];
                const float* wqr = Win + (size_t)r*32;
                #pragma unroll
                for (int j = 0; j < 32; ++j) aq = fmaf(f[sq][j], wqr[j], aq);
                qd[d] = aq;
            }
            float s0 = 0.f, s1 = 0.f, s2 = 0.f;
            #pragma unroll
            for (int d = 0; d < 8; ++d) {
                s0 = fmaf(qd[d], kk[0][d], s0);
                s1 = fmaf(qd[d], kk[1][d], s1);
                s2 = fmaf(qd[d], kk[2][d], s2);
            }
            s0 = m0 ? s0*scale : NEGV;
            s1 = m1 ? s1*scale : NEGV;
            s2 = m2 ? s2*scale : NEGV;
            float mx = fmaxf(s0, fmaxf(s1, s2));
            float e0 = __expf(s0 - mx), e1 = __expf(s1 - mx), e2 = __expf(s2 - mx);
            float inv = 1.f / (e0 + e1 + e2);
            e0 *= inv; e1 *= inv; e2 *= inv;
            #pragma unroll
            for (int d = 0; d < 8; ++d)
                ctxh[sq][d] = e0*vv[0][d] + e1*vv[1][d] + e2*vv[2][d];
        }
        // fold out-projection slice: acc[s][o] += ctxh[s]·Wout[o, h*8..h*8+7]
        #pragma unroll
        for (int s = 0; s < 3; ++s) {
            #pragma unroll
            for (int o = 0; o < 32; ++o) {
                const float* wr = Wout + (size_t)o*32 + h*8;  // uniform -> s_load
                float a = acc[s][o];
                #pragma unroll
                for (int d = 0; d < 8; ++d) a = fmaf(ctxh[s][d], wr[d], a);
                acc[s][o] = a;
            }
        }
    }

    // ---- epilogue: weighted residual + LayerNorm + weighted sum ----
    float fused[32];
    #pragma unroll
    for (int o = 0; o < 32; ++o) fused[o] = 0.f;

    #pragma unroll
    for (int s = 0; s < 3; ++s) {
        const float ws = (s == 0) ? w0 : (s == 1) ? w1 : w2;
        float row[32];
        float mu = 0.f;
        #pragma unroll
        for (int o = 0; o < 32; ++o) {
            float a = acc[s][o] + bout[o];
            row[o] = fmaf(a, ws, f[s][o]);   // attended*w + features
            mu += row[o];
        }
        mu *= (1.f/32.f);
        float var = 0.f;
        #pragma unroll
        for (int o = 0; o < 32; ++o) { float d = row[o] - mu; var = fmaf(d, d, var); }
        var *= (1.f/32.f);
        const float rs = rsqrtf(var + LN_EPS);
        #pragma unroll
        for (int o = 0; o < 32; ++o) {
            float y = (row[o] - mu) * rs * gam[o] + bet[o];
            fused[o] = fmaf(ws, y, fused[o]);
        }
    }

    #pragma unroll
    for (int i = 0; i < 8; ++i) {
        float4 r;
        r.x = fused[4*i+0]; r.y = fused[4*i+1]; r.z = fused[4*i+2]; r.w = fused[4*i+3];
        po[i] = r;
    }
}

extern "C" void kernel_launch(void* const* d_in, const int* in_sizes, int n_in,
                              void* d_out, int out_size, void* d_ws, size_t ws_size,
                              hipStream_t stream) {
    const float* metric = (const float*)d_in[0];
    const float* logx   = (const float*)d_in[1];
    const float* trace  = (const float*)d_in[2];
    const void*  masks  = d_in[3];
    const float* Win    = (const float*)d_in[4];
    const float* bin    = (const float*)d_in[5];
    const float* Wout   = (const float*)d_in[6];
    const float* bout   = (const float*)d_in[7];
    const float* mw     = (const float*)d_in[8];
    const float* gam    = (const float*)d_in[9];
    const float* bet    = (const float*)d_in[10];
    float* out = (float*)d_out;
    u32* flag = (u32*)d_ws;

    const int B = in_sizes[0] / 32;         // 262144
    const int grid = (B + 255) / 256;

    // Mask-encoding detection. Scan count must be valid under BOTH encodings:
    // byte masks -> 3B bytes = 3B/4 words; int32 masks -> 3B words. Use 3B/4.
    const int nwords = (3 * B) / 4;
    const int dgrid = (nwords / 4 + 255) / 256;

    hipMemsetAsync(flag, 0, 4, stream);
    hipLaunchKernelGGL(cmaf_detect, dim3(dgrid), dim3(256), 0, stream,
                       (const u32*)masks, flag, nwords);
    hipLaunchKernelGGL(cmaf_kernel, dim3(grid), dim3(256), 0, stream,
                       metric, logx, trace, masks, flag, Win, bin, Wout, bout,
                       mw, gam, bet, out, B);
}